// Round 1
// baseline (456.236 us; speedup 1.0000x reference)
//
#include <hip/hip_runtime.h>

#define N_ALPHA 0.8f

// -------- Edge scatter: one wave per edge, one lane per feature --------
__global__ __launch_bounds__(256) void edge_scatter(
    const float* __restrict__ feats,
    const int* __restrict__ src,
    const int* __restrict__ dst,
    const float* __restrict__ edge_w,
    float* __restrict__ sum_m,
    float* __restrict__ sum_w,
    int n_edges)
{
    int gid  = blockIdx.x * blockDim.x + threadIdx.x;
    int e    = gid >> 6;          // wave index == edge index
    int lane = threadIdx.x & 63;  // feature index
    if (e >= n_edges) return;

    int   s = src[e];
    int   d = dst[e];
    float w = edge_w[e];

    // coalesced 256B gather of the source row (feats is L2/L3 resident)
    float v = w * feats[s * 64 + lane];
    atomicAdd(&sum_m[d * 64 + lane], v);
    if (lane == 0) atomicAdd(&sum_w[d], w);
}

// -------- Node phase: aggregate + 64x64 GEMM + bias + sigmoid --------
__global__ __launch_bounds__(256) void node_update(
    const float* __restrict__ feats,
    const float* __restrict__ sum_m,
    const float* __restrict__ sum_w,
    const float* __restrict__ W,
    const float* __restrict__ b,
    float* __restrict__ out,
    int n_nodes)
{
    __shared__ float W_lds[64 * 64];   // 16 KiB
    __shared__ float agg[4][64];       // 4 nodes per 256-thread block iter

    int t  = threadIdx.x;
    int j  = t & 63;   // output column
    int ln = t >> 6;   // local node (0..3)

    for (int i = t; i < 64 * 64; i += 256) W_lds[i] = W[i];
    float bias = b[j];

    for (int tile = blockIdx.x * 4; tile < n_nodes; tile += gridDim.x * 4) {
        int n = tile + ln;
        __syncthreads();  // also covers the W_lds load on first iteration
        if (n < n_nodes) {
            float f  = feats[n * 64 + j];
            float sw = sum_w[n];
            float h  = sw > 0.0f ? sum_m[n * 64 + j] / fmaxf(sw, 1e-30f) : 0.0f;
            agg[ln][j] = N_ALPHA * f + (1.0f - N_ALPHA) * h;
        }
        __syncthreads();
        if (n < n_nodes) {
            float acc = bias;
            #pragma unroll
            for (int k = 0; k < 64; ++k)
                acc = fmaf(agg[ln][k], W_lds[k * 64 + j], acc);
            out[n * 64 + j] = 1.0f / (1.0f + expf(-acc));
        }
    }
}

extern "C" void kernel_launch(void* const* d_in, const int* in_sizes, int n_in,
                              void* d_out, int out_size, void* d_ws, size_t ws_size,
                              hipStream_t stream)
{
    const float* feats  = (const float*)d_in[0];
    const int*   src    = (const int*)d_in[1];
    const int*   dst    = (const int*)d_in[2];
    const float* edge_w = (const float*)d_in[3];
    const float* W      = (const float*)d_in[4];
    const float* b      = (const float*)d_in[5];
    float*       out    = (float*)d_out;

    const int n_nodes = in_sizes[0] / 64;
    const int n_edges = in_sizes[1];

    float* sum_m = (float*)d_ws;                       // [n_nodes * 64]
    float* sum_w = sum_m + (size_t)n_nodes * 64;       // [n_nodes]

    // zero the accumulators (ws is re-poisoned to 0xAA before every call)
    hipMemsetAsync(d_ws, 0, (size_t)(n_nodes * 64 + n_nodes) * sizeof(float), stream);

    // edge scatter: one wave per edge -> E*64 threads
    {
        long long total = (long long)n_edges * 64;
        int block = 256;
        int grid  = (int)((total + block - 1) / block);
        edge_scatter<<<grid, block, 0, stream>>>(feats, src, dst, edge_w,
                                                 sum_m, sum_w, n_edges);
    }

    // node update: grid-stride, 4 nodes per block-iteration
    {
        int block = 256;
        int grid  = 2048;
        node_update<<<grid, block, 0, stream>>>(feats, sum_m, sum_w, W, b,
                                                out, n_nodes);
    }
}

// Round 2
// 305.372 us; speedup vs baseline: 1.4940x; 1.4940x over previous
//
#include <hip/hip_runtime.h>

#define ALPHA_F 0.8f
#define D 64
#define SCAN_BLOCK 256
#define SCAN_ITEMS 4
#define SCAN_TILE (SCAN_BLOCK * SCAN_ITEMS)   // 1024 counts per scan block

// ---------------- Phase 1: histogram of in-degrees ----------------
__global__ __launch_bounds__(256) void hist_kernel(
    const int* __restrict__ dst, int* __restrict__ counts, int n_edges)
{
    int e = blockIdx.x * 256 + threadIdx.x;
    if (e < n_edges) atomicAdd(&counts[dst[e]], 1);
}

// ---------------- Phase 2: exclusive scan (3 kernels) ----------------
__global__ __launch_bounds__(SCAN_BLOCK) void scan1_kernel(
    const int* __restrict__ counts, int* __restrict__ offsets,
    int* __restrict__ partials, int n)
{
    __shared__ int tsum[SCAN_BLOCK];
    int t = threadIdx.x;
    int base = blockIdx.x * SCAN_TILE + t * SCAN_ITEMS;

    int v[SCAN_ITEMS];
    #pragma unroll
    for (int i = 0; i < SCAN_ITEMS; ++i)
        v[i] = (base + i < n) ? counts[base + i] : 0;

    int tot = 0;
    #pragma unroll
    for (int i = 0; i < SCAN_ITEMS; ++i) tot += v[i];

    tsum[t] = tot;
    __syncthreads();
    for (int off = 1; off < SCAN_BLOCK; off <<= 1) {
        int x = (t >= off) ? tsum[t - off] : 0;
        __syncthreads();
        tsum[t] += x;
        __syncthreads();
    }
    if (t == SCAN_BLOCK - 1) partials[blockIdx.x] = tsum[t];

    int run = tsum[t] - tot;   // exclusive prefix of this thread within block
    #pragma unroll
    for (int i = 0; i < SCAN_ITEMS; ++i) {
        if (base + i < n) offsets[base + i] = run;
        run += v[i];
    }
}

__global__ __launch_bounds__(1024) void scan2_kernel(int* __restrict__ partials, int nb)
{
    __shared__ int tsum[1024];
    int t = threadIdx.x;
    int v = (t < nb) ? partials[t] : 0;
    tsum[t] = v;
    __syncthreads();
    for (int off = 1; off < 1024; off <<= 1) {
        int x = (t >= off) ? tsum[t - off] : 0;
        __syncthreads();
        tsum[t] += x;
        __syncthreads();
    }
    if (t < nb) partials[t] = tsum[t] - v;   // exclusive
}

__global__ __launch_bounds__(SCAN_BLOCK) void scan3_kernel(
    int* __restrict__ offsets, int* __restrict__ cursor,
    const int* __restrict__ partials, int n, int n_edges)
{
    int t = threadIdx.x;
    int base = blockIdx.x * SCAN_TILE + t * SCAN_ITEMS;
    int add = partials[blockIdx.x];
    #pragma unroll
    for (int i = 0; i < SCAN_ITEMS; ++i) {
        int idx = base + i;
        if (idx < n) {
            int f = offsets[idx] + add;
            offsets[idx] = f;
            cursor[idx]  = f;
        }
    }
    if (blockIdx.x == 0 && t == 0) offsets[n] = n_edges;
}

// ---------------- Phase 3: scatter edges into CSR ----------------
__global__ __launch_bounds__(256) void scatter_kernel(
    const int* __restrict__ src, const int* __restrict__ dst,
    const float* __restrict__ edge_w, int* __restrict__ cursor,
    uint2* __restrict__ csr, int n_edges)
{
    int e = blockIdx.x * 256 + threadIdx.x;
    if (e < n_edges) {
        int d = dst[e];
        int pos = atomicAdd(&cursor[d], 1);
        csr[pos] = make_uint2((unsigned)src[e], __float_as_uint(edge_w[e]));
    }
}

// ---------------- Phase 4: fused gather + aggregate + GEMM + sigmoid ----------------
// One wave per node. Lane = feature index. W column held in registers;
// agg broadcast across lanes via v_readlane -> zero LDS, zero syncthreads.
__global__ __launch_bounds__(256) void node_fused_kernel(
    const float* __restrict__ feats,
    const int* __restrict__ offsets,
    const uint2* __restrict__ csr,
    const float* __restrict__ W,
    const float* __restrict__ b,
    float* __restrict__ out,
    int n_nodes)
{
    int lane   = threadIdx.x & 63;
    int wave   = (blockIdx.x * blockDim.x + threadIdx.x) >> 6;
    int nwaves = (gridDim.x * blockDim.x) >> 6;

    // per-thread copy of W column `lane` (coalesced row-wise reads, L2-hot)
    float wcol[D];
    #pragma unroll
    for (int k = 0; k < D; ++k) wcol[k] = W[k * D + lane];
    float bias = b[lane];

    for (int n = wave; n < n_nodes; n += nwaves) {
        int rs = __builtin_amdgcn_readfirstlane(offsets[n]);
        int re = __builtin_amdgcn_readfirstlane(offsets[n + 1]);

        float acc = 0.0f, sumw = 0.0f;
        int i = rs;
        for (; i + 4 <= re; i += 4) {
            uint2 p0 = csr[i + 0];
            uint2 p1 = csr[i + 1];
            uint2 p2 = csr[i + 2];
            uint2 p3 = csr[i + 3];
            float w0 = __uint_as_float(p0.y);
            float w1 = __uint_as_float(p1.y);
            float w2 = __uint_as_float(p2.y);
            float w3 = __uint_as_float(p3.y);
            acc = fmaf(w0, feats[(int)p0.x * D + lane], acc);
            acc = fmaf(w1, feats[(int)p1.x * D + lane], acc);
            acc = fmaf(w2, feats[(int)p2.x * D + lane], acc);
            acc = fmaf(w3, feats[(int)p3.x * D + lane], acc);
            sumw += w0 + w1 + w2 + w3;
        }
        for (; i < re; ++i) {
            uint2 p = csr[i];
            float w = __uint_as_float(p.y);
            acc = fmaf(w, feats[(int)p.x * D + lane], acc);
            sumw += w;
        }

        float f = feats[n * D + lane];
        float h = (sumw > 0.0f) ? acc / fmaxf(sumw, 1e-30f) : 0.0f;
        float aggv = ALPHA_F * f + (1.0f - ALPHA_F) * h;

        // 64x64 GEMM row via readlane broadcast (no LDS)
        float r = bias;
        #pragma unroll
        for (int k = 0; k < D; ++k) {
            float ak = __uint_as_float(
                __builtin_amdgcn_readlane(__float_as_uint(aggv), k));
            r = fmaf(ak, wcol[k], r);
        }
        out[n * D + lane] = 1.0f / (1.0f + __expf(-r));
    }
}

extern "C" void kernel_launch(void* const* d_in, const int* in_sizes, int n_in,
                              void* d_out, int out_size, void* d_ws, size_t ws_size,
                              hipStream_t stream)
{
    const float* feats  = (const float*)d_in[0];
    const int*   src    = (const int*)d_in[1];
    const int*   dst    = (const int*)d_in[2];
    const float* edge_w = (const float*)d_in[3];
    const float* W      = (const float*)d_in[4];
    const float* b      = (const float*)d_in[5];
    float*       out    = (float*)d_out;

    const int n_nodes = in_sizes[0] / D;
    const int n_edges = in_sizes[1];

    // ---- workspace layout (ints) ----
    int* ws_i     = (int*)d_ws;
    int* counts   = ws_i;                       // [n_nodes]
    int* offsets  = counts + n_nodes;           // [n_nodes + 1]
    int* cursor   = offsets + n_nodes + 1;      // [n_nodes]
    int* partials = cursor + n_nodes;           // [1024]
    size_t csr_off_ints = (size_t)(3 * n_nodes + 1 + 1024);
    csr_off_ints = (csr_off_ints + 1) & ~(size_t)1;     // 8B align
    uint2* csr = (uint2*)(ws_i + csr_off_ints);         // [n_edges]

    // zero only the histogram
    hipMemsetAsync(counts, 0, (size_t)n_nodes * sizeof(int), stream);

    const int nb_edges = (n_edges + 255) / 256;
    const int nb_scan  = (n_nodes + SCAN_TILE - 1) / SCAN_TILE;

    hist_kernel<<<nb_edges, 256, 0, stream>>>(dst, counts, n_edges);
    scan1_kernel<<<nb_scan, SCAN_BLOCK, 0, stream>>>(counts, offsets, partials, n_nodes);
    scan2_kernel<<<1, 1024, 0, stream>>>(partials, nb_scan);
    scan3_kernel<<<nb_scan, SCAN_BLOCK, 0, stream>>>(offsets, cursor, partials, n_nodes, n_edges);
    scatter_kernel<<<nb_edges, 256, 0, stream>>>(src, dst, edge_w, cursor, csr, n_edges);
    node_fused_kernel<<<2048, 256, 0, stream>>>(feats, offsets, csr, W, b, out, n_nodes);
}

// Round 3
// 275.374 us; speedup vs baseline: 1.6568x; 1.1089x over previous
//
#include <hip/hip_runtime.h>

#define ALPHA_F 0.8f
#define D 64
#define SCAN_BLOCK 256
#define SCAN_ITEMS 4
#define SCAN_TILE (SCAN_BLOCK * SCAN_ITEMS)   // 1024 counts per scan block
#define NRANGE 8                              // dst-range partitions (== XCDs)
#define NCHUNK 512                            // edge chunks per range

// ---------------- Phase 1: histogram of in-degrees ----------------
__global__ __launch_bounds__(256) void hist_kernel(
    const int* __restrict__ dst, int* __restrict__ counts, int n_edges)
{
    int e = blockIdx.x * 256 + threadIdx.x;
    if (e < n_edges) atomicAdd(&counts[dst[e]], 1);
}

// ---------------- Phase 2: exclusive scan (3 kernels) ----------------
__global__ __launch_bounds__(SCAN_BLOCK) void scan1_kernel(
    const int* __restrict__ counts, int* __restrict__ offsets,
    int* __restrict__ partials, int n)
{
    __shared__ int tsum[SCAN_BLOCK];
    int t = threadIdx.x;
    int base = blockIdx.x * SCAN_TILE + t * SCAN_ITEMS;

    int v[SCAN_ITEMS];
    #pragma unroll
    for (int i = 0; i < SCAN_ITEMS; ++i)
        v[i] = (base + i < n) ? counts[base + i] : 0;

    int tot = 0;
    #pragma unroll
    for (int i = 0; i < SCAN_ITEMS; ++i) tot += v[i];

    tsum[t] = tot;
    __syncthreads();
    for (int off = 1; off < SCAN_BLOCK; off <<= 1) {
        int x = (t >= off) ? tsum[t - off] : 0;
        __syncthreads();
        tsum[t] += x;
        __syncthreads();
    }
    if (t == SCAN_BLOCK - 1) partials[blockIdx.x] = tsum[t];

    int run = tsum[t] - tot;   // exclusive prefix of this thread within block
    #pragma unroll
    for (int i = 0; i < SCAN_ITEMS; ++i) {
        if (base + i < n) offsets[base + i] = run;
        run += v[i];
    }
}

__global__ __launch_bounds__(1024) void scan2_kernel(int* __restrict__ partials, int nb)
{
    __shared__ int tsum[1024];
    int t = threadIdx.x;
    int v = (t < nb) ? partials[t] : 0;
    tsum[t] = v;
    __syncthreads();
    for (int off = 1; off < 1024; off <<= 1) {
        int x = (t >= off) ? tsum[t - off] : 0;
        __syncthreads();
        tsum[t] += x;
        __syncthreads();
    }
    if (t < nb) partials[t] = tsum[t] - v;   // exclusive
}

__global__ __launch_bounds__(SCAN_BLOCK) void scan3_kernel(
    int* __restrict__ offsets, int* __restrict__ cursor,
    const int* __restrict__ partials, int n, int n_edges)
{
    int t = threadIdx.x;
    int base = blockIdx.x * SCAN_TILE + t * SCAN_ITEMS;
    int add = partials[blockIdx.x];
    #pragma unroll
    for (int i = 0; i < SCAN_ITEMS; ++i) {
        int idx = base + i;
        if (idx < n) {
            int f = offsets[idx] + add;
            offsets[idx] = f;
            cursor[idx]  = f;
        }
    }
    if (blockIdx.x == 0 && t == 0) offsets[n] = n_edges;
}

// ---------------- Phase 3: dst-range-partitioned scatter ----------------
// Block (r = blockIdx&7, chunk = blockIdx>>3) handles only edges whose dst
// falls in range r (1/8 of nodes -> 1.28 MB CSR slice). With round-robin
// block->XCD dispatch, each range's writes stay in one XCD's L2, so the
// random 8B record stores merge into full-line writebacks (81 MB -> ~12 MB).
// Correctness does not depend on the XCD mapping.
__global__ __launch_bounds__(256) void scatter_xcd_kernel(
    const int* __restrict__ src, const int* __restrict__ dst,
    const float* __restrict__ edge_w, int* __restrict__ cursor,
    uint2* __restrict__ csr, int n_edges, int range_size)
{
    int r      = blockIdx.x & (NRANGE - 1);
    int chunk  = blockIdx.x >> 3;
    int nchunk = gridDim.x >> 3;
    int per    = (n_edges + nchunk - 1) / nchunk;
    int e0     = chunk * per;
    int e1     = min(e0 + per, n_edges);
    int lo     = r * range_size;
    int hi     = lo + range_size;

    for (int e = e0 + threadIdx.x; e < e1; e += 256) {
        int d = dst[e];
        if (d >= lo && d < hi) {
            int pos = atomicAdd(&cursor[d], 1);
            csr[pos] = make_uint2((unsigned)src[e], __float_as_uint(edge_w[e]));
        }
    }
}

// ---------------- Phase 4: fused gather + aggregate + GEMM + sigmoid ----------------
__global__ __launch_bounds__(256) void node_fused_kernel(
    const float* __restrict__ feats,
    const int* __restrict__ offsets,
    const uint2* __restrict__ csr,
    const float* __restrict__ W,
    const float* __restrict__ b,
    float* __restrict__ out,
    int n_nodes)
{
    int lane   = threadIdx.x & 63;
    int wave   = (blockIdx.x * blockDim.x + threadIdx.x) >> 6;
    int nwaves = (gridDim.x * blockDim.x) >> 6;

    // per-thread copy of W column `lane` (coalesced row-wise reads, L2-hot)
    float wcol[D];
    #pragma unroll
    for (int k = 0; k < D; ++k) wcol[k] = W[k * D + lane];
    float bias = b[lane];

    for (int n = wave; n < n_nodes; n += nwaves) {
        int rs = __builtin_amdgcn_readfirstlane(offsets[n]);
        int re = __builtin_amdgcn_readfirstlane(offsets[n + 1]);

        float acc = 0.0f, sumw = 0.0f;
        int i = rs;
        for (; i + 4 <= re; i += 4) {
            uint2 p0 = csr[i + 0];
            uint2 p1 = csr[i + 1];
            uint2 p2 = csr[i + 2];
            uint2 p3 = csr[i + 3];
            float w0 = __uint_as_float(p0.y);
            float w1 = __uint_as_float(p1.y);
            float w2 = __uint_as_float(p2.y);
            float w3 = __uint_as_float(p3.y);
            acc = fmaf(w0, feats[(int)p0.x * D + lane], acc);
            acc = fmaf(w1, feats[(int)p1.x * D + lane], acc);
            acc = fmaf(w2, feats[(int)p2.x * D + lane], acc);
            acc = fmaf(w3, feats[(int)p3.x * D + lane], acc);
            sumw += w0 + w1 + w2 + w3;
        }
        for (; i < re; ++i) {
            uint2 p = csr[i];
            float w = __uint_as_float(p.y);
            acc = fmaf(w, feats[(int)p.x * D + lane], acc);
            sumw += w;
        }

        float f = feats[n * D + lane];
        float h = (sumw > 0.0f) ? acc / fmaxf(sumw, 1e-30f) : 0.0f;
        float aggv = ALPHA_F * f + (1.0f - ALPHA_F) * h;

        // 64x64 GEMM row via readlane broadcast (no LDS)
        float r = bias;
        #pragma unroll
        for (int k = 0; k < D; ++k) {
            float ak = __uint_as_float(
                __builtin_amdgcn_readlane(__float_as_uint(aggv), k));
            r = fmaf(ak, wcol[k], r);
        }
        out[n * D + lane] = 1.0f / (1.0f + __expf(-r));
    }
}

extern "C" void kernel_launch(void* const* d_in, const int* in_sizes, int n_in,
                              void* d_out, int out_size, void* d_ws, size_t ws_size,
                              hipStream_t stream)
{
    const float* feats  = (const float*)d_in[0];
    const int*   src    = (const int*)d_in[1];
    const int*   dst    = (const int*)d_in[2];
    const float* edge_w = (const float*)d_in[3];
    const float* W      = (const float*)d_in[4];
    const float* b      = (const float*)d_in[5];
    float*       out    = (float*)d_out;

    const int n_nodes = in_sizes[0] / D;
    const int n_edges = in_sizes[1];

    // ---- workspace layout (ints) ----
    int* ws_i     = (int*)d_ws;
    int* counts   = ws_i;                       // [n_nodes]
    int* offsets  = counts + n_nodes;           // [n_nodes + 1]
    int* cursor   = offsets + n_nodes + 1;      // [n_nodes]
    int* partials = cursor + n_nodes;           // [1024]
    size_t csr_off_ints = (size_t)(3 * n_nodes + 1 + 1024);
    csr_off_ints = (csr_off_ints + 1) & ~(size_t)1;     // 8B align
    uint2* csr = (uint2*)(ws_i + csr_off_ints);         // [n_edges]

    // zero only the histogram
    hipMemsetAsync(counts, 0, (size_t)n_nodes * sizeof(int), stream);

    const int nb_edges   = (n_edges + 255) / 256;
    const int nb_scan    = (n_nodes + SCAN_TILE - 1) / SCAN_TILE;
    const int range_size = (n_nodes + NRANGE - 1) / NRANGE;

    hist_kernel<<<nb_edges, 256, 0, stream>>>(dst, counts, n_edges);
    scan1_kernel<<<nb_scan, SCAN_BLOCK, 0, stream>>>(counts, offsets, partials, n_nodes);
    scan2_kernel<<<1, 1024, 0, stream>>>(partials, nb_scan);
    scan3_kernel<<<nb_scan, SCAN_BLOCK, 0, stream>>>(offsets, cursor, partials, n_nodes, n_edges);
    scatter_xcd_kernel<<<NRANGE * NCHUNK, 256, 0, stream>>>(src, dst, edge_w, cursor,
                                                            csr, n_edges, range_size);
    node_fused_kernel<<<2048, 256, 0, stream>>>(feats, offsets, csr, W, b, out, n_nodes);
}